// Round 1
// baseline (190.290 us; speedup 1.0000x reference)
//
#include <hip/hip_runtime.h>

// RoIAlign dense (11x11 bilinear grid) + 3x3/s2 max pool -> [K, C, 5, 5]
// features: [B=4, C=256, H=100, W=100] f32, rois: [K=2048, 5] f32
//
// Structure: 1 block per RoI, 4 waves of 64 lanes. Each wave handles 64
// channels. Sample coords/weights depend only on (roi, grid point) ->
// precomputed per lane before the channel loop. Per channel: 121 dense
// samples in 2 lane-rounds (4 gathers + bilinear), staged in a per-wave
// double-buffered LDS tile (wave-lockstep, no block barrier needed),
// then lanes 0..24 compute the 3x3/s2 max and store 25 contiguous floats.

constexpr int Cc = 256;
constexpr int Hh = 100;
constexpr int Ww = 100;
constexpr float SCALE = 0.0625f;

__global__ __launch_bounds__(256)
void roialign_pool_kernel(const float* __restrict__ feats,
                          const float* __restrict__ rois,
                          float* __restrict__ out)
{
    __shared__ float smem[4][2][128];   // [wave][parity][sample slot]

    const int k    = blockIdx.x;
    const int tid  = threadIdx.x;
    const int wid  = tid >> 6;
    const int lane = tid & 63;

    // RoI params (uniform within block -> scalar loads)
    const float bidx = rois[k * 5 + 0];
    const float x1   = rois[k * 5 + 1] * SCALE;
    const float y1   = rois[k * 5 + 2] * SCALE;
    const float x2   = rois[k * 5 + 3] * SCALE;
    const float y2   = rois[k * 5 + 4] * SCALE;
    const int   b    = (int)bidx;

    // Per-lane sample params: round 0 -> grid point `lane`, round 1 -> 64+lane.
    // All loop-invariant over channels.
    const int  p1   = 64 + lane;
    const bool act1 = (p1 < 121);

    int   o00[2], o01[2], o10[2], o11[2];
    float w00[2], w01[2], w10[2], w11[2];
    const int pp0 = lane;
    const int pp1 = act1 ? p1 : 120;   // clamp inactive lanes to a valid point

#pragma unroll
    for (int r = 0; r < 2; ++r) {
        const int p  = (r == 0) ? pp0 : pp1;
        const int gy = p / 11;
        const int gx = p - gy * 11;
        const float ys = y1 + (y2 - y1) * ((float)gy / 10.0f);
        const float xs = x1 + (x2 - x1) * ((float)gx / 10.0f);
        const float y0f = floorf(ys);
        const float x0f = floorf(xs);
        const float wy = ys - y0f;      // weights from UNCLIPPED coords (ref semantics)
        const float wx = xs - x0f;
        const int y0i = (int)y0f;
        const int x0i = (int)x0f;
        const int y0c = min(max(y0i,     0), Hh - 1);
        const int y1c = min(max(y0i + 1, 0), Hh - 1);
        const int x0c = min(max(x0i,     0), Ww - 1);
        const int x1c = min(max(x0i + 1, 0), Ww - 1);
        o00[r] = y0c * Ww + x0c;
        o01[r] = y0c * Ww + x1c;
        o10[r] = y1c * Ww + x0c;
        o11[r] = y1c * Ww + x1c;
        w00[r] = (1.0f - wy) * (1.0f - wx);
        w01[r] = (1.0f - wy) * wx;
        w10[r] = wy * (1.0f - wx);
        w11[r] = wy * wx;
    }

    // Pooling lane setup (lanes 0..24 produce the 5x5 pooled outputs)
    const bool pool  = (lane < 25);
    const int  ph    = lane / 5;
    const int  pw    = lane - ph * 5;
    const int  pbase = (2 * ph) * 11 + 2 * pw;

    // This wave's 64 channels start at wid*64
    const float* base = feats + ((size_t)b * Cc + (size_t)wid * 64) * (Hh * Ww);
    float*       op   = out + ((size_t)k * Cc + (size_t)wid * 64) * 25 + lane;

    for (int it = 0; it < 64; ++it) {
        const float* f   = base + (size_t)it * (Hh * Ww);
        float*       buf = smem[wid][it & 1];

        const float v0 = f[o00[0]] * w00[0] + f[o01[0]] * w01[0]
                       + f[o10[0]] * w10[0] + f[o11[0]] * w11[0];
        const float v1 = f[o00[1]] * w00[1] + f[o01[1]] * w01[1]
                       + f[o10[1]] * w10[1] + f[o11[1]] * w11[1];

        buf[lane] = v0;
        if (act1) buf[p1] = v1;
        // Same-wave LDS RAW: compiler inserts lgkmcnt waits (aliasing on smem);
        // wave is lockstep; parity double-buffer removes WAR across iterations.

        if (pool) {
            float m =          buf[pbase +  0];
            m = fmaxf(m, buf[pbase +  1]);
            m = fmaxf(m, buf[pbase +  2]);
            m = fmaxf(m, buf[pbase + 11]);
            m = fmaxf(m, buf[pbase + 12]);
            m = fmaxf(m, buf[pbase + 13]);
            m = fmaxf(m, buf[pbase + 22]);
            m = fmaxf(m, buf[pbase + 23]);
            m = fmaxf(m, buf[pbase + 24]);
            op[it * 25] = m;
        }
    }
}

extern "C" void kernel_launch(void* const* d_in, const int* in_sizes, int n_in,
                              void* d_out, int out_size, void* d_ws, size_t ws_size,
                              hipStream_t stream) {
    const float* feats = (const float*)d_in[0];
    const float* rois  = (const float*)d_in[1];
    float*       out   = (float*)d_out;
    const int K = in_sizes[1] / 5;   // 2048
    roialign_pool_kernel<<<K, 256, 0, stream>>>(feats, rois, out);
}

// Round 2
// 62.436 us; speedup vs baseline: 3.0478x; 3.0478x over previous
//
#include <hip/hip_runtime.h>

// RoIAlign dense (11x11 bilinear) + 3x3/s2 max pool -> [K=2048, C=256, 5, 5]
// features: [B=4, C=256, H=100, W=100] f32 (NCHW), rois: [K,5] f32
//
// R1 was L1/TA line-throughput bound: gathers with lanes = spatial points
// touch ~18 cache lines per load instruction. R2: pre-transpose features to
// NHWC (one extra 82 MB pass), then map lane = channel so every tap load is
// 64 consecutive floats (256 B = 4 lines). Coordinates/weights are
// wave-uniform; pooling is separable per-lane register max (no LDS hot path).
// Output staged through a small LDS buffer for coalesced stores.

constexpr int Bn = 4, Cn = 256, Hn = 100, Wn = 100;
constexpr int HWn = Hn * Wn;
constexpr float SCALE = 0.0625f;

// ---------------- Kernel 1: NCHW -> NHWC transpose ----------------
__global__ __launch_bounds__(256)
void nchw_to_nhwc(const float* __restrict__ in, float* __restrict__ out)
{
    __shared__ float tile[64][65];          // +1 pad: conflict-free both ways
    const int s0 = blockIdx.x * 64;         // spatial tile start
    const int c0 = blockIdx.y * 64;         // channel tile start
    const int b  = blockIdx.z;
    const int tid = threadIdx.x;
    const int a = tid & 63;
    const int g = tid >> 6;                 // 0..3

    const float* ip = in + ((size_t)b * Cn + c0) * HWn + s0;
#pragma unroll
    for (int r = 0; r < 16; ++r) {
        const int c = g * 16 + r;
        tile[c][a] = (s0 + a < HWn) ? ip[(size_t)c * HWn + a] : 0.0f;
    }
    __syncthreads();
    float* op = out + ((size_t)b * HWn + s0) * Cn + c0;
#pragma unroll
    for (int r = 0; r < 16; ++r) {
        const int s = g * 16 + r;
        if (s0 + s < HWn) op[(size_t)s * Cn + a] = tile[a][s];
    }
}

// ---------------- Kernel 2: RoIAlign+pool, lane = channel ----------------
__global__ __launch_bounds__(256)
void roipool_nhwc(const float* __restrict__ f, const float* __restrict__ rois,
                  float* __restrict__ out)
{
    __shared__ float stage[4][800];         // [wave][32ch * 25], 12.8 KB
    const int k    = blockIdx.x;
    const int tid  = threadIdx.x;
    const int wid  = tid >> 6;
    const int lane = tid & 63;

    const float x1 = rois[k * 5 + 1] * SCALE;
    const float y1 = rois[k * 5 + 2] * SCALE;
    const float x2 = rois[k * 5 + 3] * SCALE;
    const float y2 = rois[k * 5 + 4] * SCALE;
    const int   b  = (int)rois[k * 5 + 0];

    // lane's channel pointer into NHWC features
    const float* fb = f + (size_t)b * HWn * Cn + (wid * 64 + lane);

    float o[25];        // pooled outputs for this lane's channel
    float xp_prev[5];   // x-pooled maxes of the previously computed dense row

    // Compute one dense sample row gy (11 bilinear samples), reduced to the
    // 5 x-window maxes. All coords wave-uniform; taps are 256 B coalesced.
    auto xpool = [&](int gy, float dst[5]) {
        const float ys  = y1 + (y2 - y1) * ((float)gy * 0.1f);
        const float y0f = floorf(ys);
        const float wy  = ys - y0f;                  // weight from UNCLIPPED coord
        const int   y0i = (int)y0f;
        const int   r0  = min(max(y0i,     0), Hn - 1);
        const int   r1  = min(max(y0i + 1, 0), Hn - 1);
        const float* row0 = fb + (size_t)(r0 * Wn) * Cn;
        const float* row1 = fb + (size_t)(r1 * Wn) * Cn;
#pragma unroll
        for (int j = 0; j < 11; ++j) {
            const float xs  = x1 + (x2 - x1) * ((float)j * 0.1f);
            const float x0f = floorf(xs);
            const float wx  = xs - x0f;
            const int   x0i = (int)x0f;
            const int   xc0 = min(max(x0i,     0), Wn - 1);
            const int   xc1 = min(max(x0i + 1, 0), Wn - 1);
            const float t00 = row0[xc0 * Cn];
            const float t01 = row0[xc1 * Cn];
            const float t10 = row1[xc0 * Cn];
            const float t11 = row1[xc1 * Cn];
            const float w11v = wy * wx;
            const float w10v = wy - w11v;            // wy*(1-wx)
            const float w01v = wx - w11v;            // (1-wy)*wx
            const float w00v = 1.0f - wy - wx + w11v;
            const float s = t00 * w00v + t01 * w01v + t10 * w10v + t11 * w11v;
            // x window pw covers j = 2pw..2pw+2 (compile-time mapping)
            if (j == 0) {
                dst[0] = s;
            } else if (j & 1) {
                dst[j >> 1] = fmaxf(dst[j >> 1], s);
            } else {
                dst[(j >> 1) - 1] = fmaxf(dst[(j >> 1) - 1], s);
                if (j < 10) dst[j >> 1] = s;
            }
        }
    };

    xpool(0, xp_prev);
#pragma unroll
    for (int ph = 0; ph < 5; ++ph) {
        float t[5], acc[5];
        xpool(2 * ph + 1, t);
#pragma unroll
        for (int pw = 0; pw < 5; ++pw) acc[pw] = fmaxf(xp_prev[pw], t[pw]);
        xpool(2 * ph + 2, xp_prev);                  // row 2ph+2 reused as next 2ph
#pragma unroll
        for (int pw = 0; pw < 5; ++pw) o[ph * 5 + pw] = fmaxf(acc[pw], xp_prev[pw]);
    }

    // Coalesced store: stage 32 channels x 25 outputs per wave at a time,
    // then write 800 consecutive floats. Same-wave LDS ops are in-order;
    // asm memory clobber stops compiler reordering across phases.
    const size_t obase = ((size_t)k * Cn + (size_t)wid * 64) * 25;
#pragma unroll
    for (int half = 0; half < 2; ++half) {
        if ((lane >> 5) == half) {
#pragma unroll
            for (int p = 0; p < 25; ++p)
                stage[wid][(lane & 31) * 25 + p] = o[p];
        }
        asm volatile("" ::: "memory");
#pragma unroll
        for (int i = 0; i < 13; ++i) {
            const int idx = i * 64 + lane;
            if (idx < 800)
                out[obase + (size_t)half * 800 + idx] = stage[wid][idx];
        }
        asm volatile("" ::: "memory");
    }
}

// ---------------- Fallback (R1 kernel) if workspace too small ----------------
__global__ __launch_bounds__(256)
void roialign_pool_fallback(const float* __restrict__ feats,
                            const float* __restrict__ rois,
                            float* __restrict__ out)
{
    __shared__ float smem[4][2][128];
    const int k    = blockIdx.x;
    const int tid  = threadIdx.x;
    const int wid  = tid >> 6;
    const int lane = tid & 63;

    const float x1 = rois[k * 5 + 1] * SCALE;
    const float y1 = rois[k * 5 + 2] * SCALE;
    const float x2 = rois[k * 5 + 3] * SCALE;
    const float y2 = rois[k * 5 + 4] * SCALE;
    const int   b  = (int)rois[k * 5 + 0];

    const int  p1   = 64 + lane;
    const bool act1 = (p1 < 121);
    int   o00[2], o01[2], o10[2], o11[2];
    float w00[2], w01[2], w10[2], w11[2];
#pragma unroll
    for (int r = 0; r < 2; ++r) {
        const int p  = (r == 0) ? lane : (act1 ? p1 : 120);
        const int gy = p / 11;
        const int gx = p - gy * 11;
        const float ys = y1 + (y2 - y1) * ((float)gy / 10.0f);
        const float xs = x1 + (x2 - x1) * ((float)gx / 10.0f);
        const float y0f = floorf(ys), x0f = floorf(xs);
        const float wy = ys - y0f, wx = xs - x0f;
        const int y0i = (int)y0f, x0i = (int)x0f;
        const int y0c = min(max(y0i, 0), Hn - 1), y1c = min(max(y0i + 1, 0), Hn - 1);
        const int x0c = min(max(x0i, 0), Wn - 1), x1c = min(max(x0i + 1, 0), Wn - 1);
        o00[r] = y0c * Wn + x0c; o01[r] = y0c * Wn + x1c;
        o10[r] = y1c * Wn + x0c; o11[r] = y1c * Wn + x1c;
        w00[r] = (1.0f - wy) * (1.0f - wx); w01[r] = (1.0f - wy) * wx;
        w10[r] = wy * (1.0f - wx);          w11[r] = wy * wx;
    }
    const bool pool  = (lane < 25);
    const int  ph    = lane / 5;
    const int  pw    = lane - ph * 5;
    const int  pbase = (2 * ph) * 11 + 2 * pw;
    const float* base = feats + ((size_t)b * Cn + (size_t)wid * 64) * HWn;
    float*       op   = out + ((size_t)k * Cn + (size_t)wid * 64) * 25 + lane;
    for (int it = 0; it < 64; ++it) {
        const float* ff  = base + (size_t)it * HWn;
        float*       buf = smem[wid][it & 1];
        const float v0 = ff[o00[0]] * w00[0] + ff[o01[0]] * w01[0]
                       + ff[o10[0]] * w10[0] + ff[o11[0]] * w11[0];
        const float v1 = ff[o00[1]] * w00[1] + ff[o01[1]] * w01[1]
                       + ff[o10[1]] * w10[1] + ff[o11[1]] * w11[1];
        buf[lane] = v0;
        if (act1) buf[p1] = v1;
        if (pool) {
            float m =          buf[pbase +  0];
            m = fmaxf(m, buf[pbase +  1]);
            m = fmaxf(m, buf[pbase +  2]);
            m = fmaxf(m, buf[pbase + 11]);
            m = fmaxf(m, buf[pbase + 12]);
            m = fmaxf(m, buf[pbase + 13]);
            m = fmaxf(m, buf[pbase + 22]);
            m = fmaxf(m, buf[pbase + 23]);
            m = fmaxf(m, buf[pbase + 24]);
            op[it * 25] = m;
        }
    }
}

extern "C" void kernel_launch(void* const* d_in, const int* in_sizes, int n_in,
                              void* d_out, int out_size, void* d_ws, size_t ws_size,
                              hipStream_t stream) {
    const float* feats = (const float*)d_in[0];
    const float* rois  = (const float*)d_in[1];
    float*       out   = (float*)d_out;
    const int K = in_sizes[1] / 5;                       // 2048
    const size_t need = (size_t)Bn * Cn * HWn * sizeof(float);  // 40.96 MB

    if (ws_size >= need) {
        float* nhwc = (float*)d_ws;
        dim3 tgrid((HWn + 63) / 64, Cn / 64, Bn);        // 157 x 4 x 4
        nchw_to_nhwc<<<tgrid, 256, 0, stream>>>(feats, nhwc);
        roipool_nhwc<<<K, 256, 0, stream>>>(nhwc, rois, out);
    } else {
        roialign_pool_fallback<<<K, 256, 0, stream>>>(feats, rois, out);
    }
}